// Round 2
// baseline (379.352 us; speedup 1.0000x reference)
//
#include <hip/hip_runtime.h>
#include <math.h>

// ComponentPointPredictor: ragged autoregressive point prediction.
// One 256-thread workgroup processes IT=4 batch items (amortizes weight
// reads 4x). Matvec accumulation in fp64 (closest to exact), but the
// temp-50000 softmax -> soft-argmax -> floor chain is done in fp32
// mirroring the reference op-for-op: in fp32 the near-hard softmax
// SNAPS p@jW to exactly j* (tails vanish below 2^-24), keeping
// seq_end's fraction stable under floor. fp64 there keeps tiny negative
// tails -> floor off-by-one -> trajectory divergence (the absmax=29).

#define CTX     256
#define INIT    32
#define HID     256
#define WIN     63
#define MSTEPS  224            // CTX - INIT
#define OUTROW  (MSTEPS + CTX) // 480
#define IT      4
#define NT      256

__global__ void __launch_bounds__(NT)
cpp_kernel(const float* __restrict__ x,
           const float* __restrict__ hid_W,
           const float* __restrict__ hid_b,
           const float* __restrict__ in_W,
           const float* __restrict__ in_b,
           const float* __restrict__ pred_W,
           const float* __restrict__ pred_b,
           float* __restrict__ out)
{
    __shared__ float  s_x[IT][CTX];      // 4 KB
    __shared__ float  s_hid[IT][HID];    // 4 KB fp32 hidden carry (matches ref)
    __shared__ double s_pred[IT][4][64]; // 8 KB split-k partials
    __shared__ float  s_last[IT];
    __shared__ int    s_lastl[IT];
    __shared__ int    s_act[IT];

    const int tid   = threadIdx.x;
    const int lane  = tid & 63;
    const int q     = tid >> 6;          // wave index 0..3
    const int item0 = blockIdx.x * IT;

    #pragma unroll
    for (int it = 0; it < IT; ++it) {
        s_x[it][tid]   = x[(size_t)(item0 + it) * CTX + tid];
        s_hid[it][tid] = 1.0f;
    }
    for (int idx = tid; idx < IT * OUTROW; idx += NT)
        out[(size_t)item0 * OUTROW + idx] = 0.0f;
    if (tid < IT) { s_last[tid] = (float)INIT; s_lastl[tid] = INIT; s_act[tid] = 1; }
    __syncthreads();

    int sc = 0;  // per-wave pts counter (wave q owns item q)

    for (int iter = 0; iter < MSTEPS; ++iter) {
        int lastl[IT], act[IT];
        #pragma unroll
        for (int it = 0; it < IT; ++it) { lastl[it] = s_lastl[it]; act[it] = s_act[it]; }
        if (!(act[0] | act[1] | act[2] | act[3])) break;

        // ---- Phase A: pre-activation for hidden unit j = tid, all IT items ----
        const int j = tid;
        double acc[IT];
        {
            const double b = (double)hid_b[j] + (double)in_b[j];
            #pragma unroll
            for (int it = 0; it < IT; ++it) acc[it] = b;
        }

        int sb[IT];
        #pragma unroll
        for (int it = 0; it < IT; ++it)
            sb[it] = (lastl[it] < CTX ? lastl[it] : CTX) - INIT;  // clamp inactive (dead lanes)

        #pragma unroll 4
        for (int m = 0; m < INIT; ++m) {
            const double wv = (double)in_W[m * HID + j];
            #pragma unroll
            for (int it = 0; it < IT; ++it)
                acc[it] = fma((double)s_x[it][sb[it] + m], wv, acc[it]);
        }

        for (int k = 0; k < HID; k += 4) {
            float hv[IT][4];
            #pragma unroll
            for (int it = 0; it < IT; ++it) {
                const float4 v = *(const float4*)&s_hid[it][k];
                hv[it][0] = v.x; hv[it][1] = v.y; hv[it][2] = v.z; hv[it][3] = v.w;
            }
            #pragma unroll
            for (int u = 0; u < 4; ++u) {
                const double wv = (double)hid_W[(size_t)(k + u) * HID + j];
                #pragma unroll
                for (int it = 0; it < IT; ++it)
                    acc[it] = fma((double)hv[it][u], wv, acc[it]);
            }
        }

        float nh[IT];
        #pragma unroll
        for (int it = 0; it < IT; ++it) nh[it] = tanhf((float)acc[it]);  // fp32 tanh like ref

        __syncthreads();
        #pragma unroll
        for (int it = 0; it < IT; ++it) if (act[it]) s_hid[it][j] = nh[it];
        __syncthreads();

        // ---- Phase B: w = nh @ pred_W, split-k: wave q covers k in [64q, 64q+64) ----
        double pacc[IT] = {0.0, 0.0, 0.0, 0.0};
        if (lane < WIN) {
            const int k0 = q * 64;
            #pragma unroll 4
            for (int kk = 0; kk < 64; ++kk) {
                const int k = k0 + kk;
                const double wv = (double)pred_W[k * WIN + lane];
                #pragma unroll
                for (int it = 0; it < IT; ++it)
                    pacc[it] = fma((double)s_hid[it][k], wv, pacc[it]);
            }
        }
        #pragma unroll
        for (int it = 0; it < IT; ++it) s_pred[it][q][lane] = pacc[it];
        __syncthreads();

        // ---- Phase C: wave q owns item q: fp32 softmax chain (mirrors ref) ----
        {
            const int it = q;
            float t = -INFINITY;
            if (lane < WIN) {
                const double wv = s_pred[it][0][lane] + s_pred[it][1][lane]
                                + s_pred[it][2][lane] + s_pred[it][3][lane]
                                + (double)pred_b[lane];
                const float wf = (float)wv;          // round to fp32 like ref's w
                t = wf * 50000.0f;                   // fp32 temp scale
            }
            float mx = t;
            #pragma unroll
            for (int off = 32; off > 0; off >>= 1)
                mx = fmaxf(mx, __shfl_xor(mx, off));
            const float e = (lane < WIN) ? expf(t - mx) : 0.0f;
            float S = e;
            #pragma unroll
            for (int off = 32; off > 0; off >>= 1)
                S += __shfl_xor(S, off);
            const float p = e / S;                   // ref divides elementwise first
            float D = p * (float)lane;
            #pragma unroll
            for (int off = 32; off > 0; off >>= 1)
                D += __shfl_xor(D, off);
            float cur = D + 1.0f;                    // soft-argmax + 1 (fp32)
            cur = fminf(cur, 63.0f);
            const float lastf = s_last[it];
            float se = cur + lastf;                  // fp32 like ref
            se = fminf(se, 256.0f);
            const int sel = (int)se;

            if (act[it]) {
                float* orow = out + (size_t)(item0 + it) * OUTROW;
                if (lane < WIN) {
                    const int pos = lastl[it] + lane;
                    if (pos < sel) {
                        // mask = 1 - sigmoid(j - cur) = 1/(1+exp(j-cur)), fp32
                        const float msk = 1.0f / (1.0f + expf((float)lane - cur));
                        orow[MSTEPS + pos] = msk * s_x[it][pos];
                    }
                }
                if (lane == 0) {
                    // the final active step always has se == 256.0 exactly -> dropped pt
                    if (se < 256.0f) orow[sc] = se;
                    s_last[it]  = se;
                    s_lastl[it] = sel;
                    s_act[it]   = (se < 256.0f) ? 1 : 0;
                }
                sc++;
            }
        }
        __syncthreads();
    }
}

extern "C" void kernel_launch(void* const* d_in, const int* in_sizes, int n_in,
                              void* d_out, int out_size, void* d_ws, size_t ws_size,
                              hipStream_t stream) {
    const float* x      = (const float*)d_in[0];
    const float* hid_W  = (const float*)d_in[1];
    const float* hid_b  = (const float*)d_in[2];
    const float* in_W   = (const float*)d_in[3];
    const float* in_b   = (const float*)d_in[4];
    const float* pred_W = (const float*)d_in[5];
    const float* pred_b = (const float*)d_in[6];
    float* out = (float*)d_out;

    const int B = in_sizes[0] / CTX;          // 4096
    const int nblocks = B / IT;               // 1024
    cpp_kernel<<<nblocks, NT, 0, stream>>>(x, hid_W, hid_b, in_W, in_b,
                                           pred_W, pred_b, out);
}

// Round 3
// 328.889 us; speedup vs baseline: 1.1534x; 1.1534x over previous
//
#include <hip/hip_runtime.h>
#include <math.h>

// ComponentPointPredictor: ragged autoregressive point prediction.
// NT=512: thread (half=tid>>8, j=tid&255) computes a k-split half of the
// 288-long dot product for hidden unit j of IT=4 items (split-k doubles
// occupancy: 32 waves/CU if VGPR<=64). s_hid / s_x are stored as fp64 in
// LDS so the fp64 FMAs need no per-element v_cvt_f64_f32 (weights are
// converted once and reused IT times). The temp-50000 softmax -> floor
// chain stays in fp32 mirroring the reference op-for-op (fp32 snaps
// p@jW to the argmax exactly; proven safe in round 2).

#define CTX     256
#define INIT    32
#define HID     256
#define WIN     63
#define MSTEPS  224            // CTX - INIT
#define OUTROW  (MSTEPS + CTX) // 480
#define IT      4
#define NT      512
#define KSPLIT  112            // half0: in_W + k<112 (144 MACs); half1: k in [112,256) (144 MACs)

__global__ void __launch_bounds__(NT)
cpp_kernel(const float* __restrict__ x,
           const float* __restrict__ hid_W,
           const float* __restrict__ hid_b,
           const float* __restrict__ in_W,
           const float* __restrict__ in_b,
           const float* __restrict__ pred_W,
           const float* __restrict__ pred_b,
           float* __restrict__ out)
{
    __shared__ double s_x[IT][CTX];       // 8 KB  fp64 copy of x rows
    __shared__ double s_hid[IT][HID];     // 8 KB  fp64 hidden carry
    __shared__ double s_scr[IT][8][64];   // 16 KB: A-reduce partials / B split-k partials (barrier-aliased)
    __shared__ float  s_last[IT];
    __shared__ int    s_lastl[IT];
    __shared__ int    s_act[IT];

    const int tid   = threadIdx.x;
    const int lane  = tid & 63;
    const int q     = tid >> 6;          // wave 0..7
    const int j     = tid & (HID - 1);   // hidden unit
    const int half  = tid >> 8;          // k-split half 0/1
    const int item0 = blockIdx.x * IT;

    // ---- init ----
    for (int idx = tid; idx < IT * CTX; idx += NT)
        s_x[idx >> 8][idx & 255] = (double)x[(size_t)(item0 + (idx >> 8)) * CTX + (idx & 255)];
    for (int idx = tid; idx < IT * HID; idx += NT)
        s_hid[idx >> 8][idx & 255] = 1.0;
    for (int idx = tid; idx < IT * OUTROW; idx += NT)
        out[(size_t)item0 * OUTROW + idx] = 0.0f;
    if (tid < IT) { s_last[tid] = (float)INIT; s_lastl[tid] = INIT; s_act[tid] = 1; }

    // per-thread constant: bias for unit j (only half0 adds it)
    const double bias = (half == 0) ? ((double)hid_b[j] + (double)in_b[j]) : 0.0;
    double* const red = &s_scr[0][0][0];  // [IT*HID] view for the A-reduce

    __syncthreads();

    int sc = 0;  // per-wave pts counter (wave q<4 owns item q)

    for (int iter = 0; iter < MSTEPS; ++iter) {
        int lastl[IT], act[IT];
        #pragma unroll
        for (int it = 0; it < IT; ++it) { lastl[it] = s_lastl[it]; act[it] = s_act[it]; }
        if (!(act[0] | act[1] | act[2] | act[3])) break;

        // ---- Phase A: partial pre-activation for unit j, k-half `half`, all IT items ----
        double acc[IT];
        #pragma unroll
        for (int it = 0; it < IT; ++it) acc[it] = bias;

        if (half == 0) {
            int sb[IT];
            #pragma unroll
            for (int it = 0; it < IT; ++it) sb[it] = lastl[it] - INIT;  // <= 224, in-bounds
            #pragma unroll 4
            for (int m = 0; m < INIT; ++m) {
                const double wv = (double)in_W[m * HID + j];
                #pragma unroll
                for (int it = 0; it < IT; ++it)
                    acc[it] = fma(s_x[it][sb[it] + m], wv, acc[it]);
            }
        }

        {
            const int kbeg = (half == 0) ? 0 : KSPLIT;
            const int kend = (half == 0) ? KSPLIT : HID;
            for (int k = kbeg; k < kend; k += 4) {
                double2 hA[IT], hB[IT];
                #pragma unroll
                for (int it = 0; it < IT; ++it) {
                    hA[it] = *(const double2*)&s_hid[it][k];
                    hB[it] = *(const double2*)&s_hid[it][k + 2];
                }
                const double w0 = (double)hid_W[(size_t)(k + 0) * HID + j];
                const double w1 = (double)hid_W[(size_t)(k + 1) * HID + j];
                const double w2 = (double)hid_W[(size_t)(k + 2) * HID + j];
                const double w3 = (double)hid_W[(size_t)(k + 3) * HID + j];
                #pragma unroll
                for (int it = 0; it < IT; ++it) {
                    acc[it] = fma(hA[it].x, w0, acc[it]);
                    acc[it] = fma(hA[it].y, w1, acc[it]);
                    acc[it] = fma(hB[it].x, w2, acc[it]);
                    acc[it] = fma(hB[it].y, w3, acc[it]);
                }
            }
        }

        if (half == 1) {
            #pragma unroll
            for (int it = 0; it < IT; ++it) red[it * HID + j] = acc[it];
        }
        __syncthreads();   // (1) all old-s_hid reads done; half1 partials visible

        if (half == 0) {
            float nh[IT];
            #pragma unroll
            for (int it = 0; it < IT; ++it) {
                acc[it] += red[it * HID + j];
                nh[it] = tanhf((float)acc[it]);
            }
            #pragma unroll
            for (int it = 0; it < IT; ++it)
                if (act[it]) s_hid[it][j] = (double)nh[it];
        }
        __syncthreads();   // (2) new hidden visible; scratch free for Phase B

        // ---- Phase B: w = hid @ pred_W, split-k over 8 waves (32 k each) ----
        double pacc[IT] = {0.0, 0.0, 0.0, 0.0};
        if (lane < WIN) {
            const int kb = q * 32;
            #pragma unroll 4
            for (int kk = 0; kk < 32; ++kk) {
                const int k = kb + kk;
                const double wv = (double)pred_W[k * WIN + lane];
                #pragma unroll
                for (int it = 0; it < IT; ++it)
                    pacc[it] = fma(s_hid[it][k], wv, pacc[it]);
            }
        }
        #pragma unroll
        for (int it = 0; it < IT; ++it) s_scr[it][q][lane] = pacc[it];
        __syncthreads();   // (3) B partials visible

        // ---- Phase C: wave q<4 owns item q: fp32 softmax chain (mirrors ref) ----
        if (q < IT) {
            const int it = q;
            float t = -INFINITY;
            if (lane < WIN) {
                const double wv = s_scr[it][0][lane] + s_scr[it][1][lane]
                                + s_scr[it][2][lane] + s_scr[it][3][lane]
                                + s_scr[it][4][lane] + s_scr[it][5][lane]
                                + s_scr[it][6][lane] + s_scr[it][7][lane]
                                + (double)pred_b[lane];
                t = (float)wv * 50000.0f;            // fp32 temp scale like ref
            }
            float mx = t;
            #pragma unroll
            for (int off = 32; off > 0; off >>= 1)
                mx = fmaxf(mx, __shfl_xor(mx, off));
            const float e = (lane < WIN) ? expf(t - mx) : 0.0f;
            float S = e;
            #pragma unroll
            for (int off = 32; off > 0; off >>= 1)
                S += __shfl_xor(S, off);
            const float p = e / S;
            float D = p * (float)lane;
            #pragma unroll
            for (int off = 32; off > 0; off >>= 1)
                D += __shfl_xor(D, off);
            float cur = D + 1.0f;
            cur = fminf(cur, 63.0f);
            float se = cur + s_last[it];
            se = fminf(se, 256.0f);
            const int sel = (int)se;

            if (act[it]) {
                float* orow = out + (size_t)(item0 + it) * OUTROW;
                if (lane < WIN) {
                    const int pos = lastl[it] + lane;
                    if (pos < sel) {
                        const float msk = 1.0f / (1.0f + expf((float)lane - cur));
                        orow[MSTEPS + pos] = msk * (float)s_x[it][pos];
                    }
                }
                if (lane == 0) {
                    // final active step has se == 256.0 exactly -> that pt is dropped
                    if (se < 256.0f) orow[sc] = se;
                    s_last[it]  = se;
                    s_lastl[it] = sel;
                    s_act[it]   = (se < 256.0f) ? 1 : 0;
                }
                sc++;
            }
        }
        __syncthreads();   // (4) state updates visible; scratch free for next A
    }
}

extern "C" void kernel_launch(void* const* d_in, const int* in_sizes, int n_in,
                              void* d_out, int out_size, void* d_ws, size_t ws_size,
                              hipStream_t stream) {
    const float* x      = (const float*)d_in[0];
    const float* hid_W  = (const float*)d_in[1];
    const float* hid_b  = (const float*)d_in[2];
    const float* in_W   = (const float*)d_in[3];
    const float* in_b   = (const float*)d_in[4];
    const float* pred_W = (const float*)d_in[5];
    const float* pred_b = (const float*)d_in[6];
    float* out = (float*)d_out;

    const int B = in_sizes[0] / CTX;          // 4096
    const int nblocks = B / IT;               // 1024
    cpp_kernel<<<nblocks, NT, 0, stream>>>(x, hid_W, hid_b, in_W, in_b,
                                           pred_W, pred_b, out);
}

// Round 4
// 318.586 us; speedup vs baseline: 1.1907x; 1.0323x over previous
//
#include <hip/hip_runtime.h>
#include <math.h>

// ComponentPointPredictor: ragged autoregressive point prediction.
// PERSISTENT version: 512 blocks x IT=4 slots = 2048 resident slots; the
// other 2048 items are claimed from a global atomic queue (d_ws) when a
// slot's item finishes. Kills the convoy tail (block time was max over 4
// items' ragged step counts) and dead-slot waste that capped round 3 at
// OccupancyPercent=32.
// Numerics (verified rounds 2-3, absmax 0.023): fp64 matvec accumulation;
// fp32 temp-50000 softmax -> soft-argmax -> floor chain op-for-op like the
// reference (fp32 snaps p@jW to the argmax; fp64 there causes floor
// off-by-one trajectory divergence).

#define CTX     256
#define INIT    32
#define HID     256
#define WIN     63
#define MSTEPS  224            // CTX - INIT
#define OUTROW  (MSTEPS + CTX) // 480
#define IT      4
#define NT      512
#define KSPLIT  112            // half0: in_W + k<112 (144 MACs); half1: k in [112,256)
#define NBLK    512
#define NSLOT   (NBLK * IT)    // 2048

__global__ void init_counter_kernel(int* cnt, int v) { *cnt = v; }

__global__ void __launch_bounds__(NT)
cpp_kernel(const float* __restrict__ x,
           const float* __restrict__ hid_W,
           const float* __restrict__ hid_b,
           const float* __restrict__ in_W,
           const float* __restrict__ in_b,
           const float* __restrict__ pred_W,
           const float* __restrict__ pred_b,
           float* __restrict__ out,
           int* __restrict__ cnt, int B)
{
    __shared__ double s_x[IT][CTX];       // 8 KB  fp64 x rows (uniform-broadcast reads)
    __shared__ double s_hid[IT][HID];     // 8 KB  fp64 hidden carry
    __shared__ double s_scr[IT][8][64];   // 16 KB A-reduce / B split-k partials (aliased)
    __shared__ int    s_lastl[IT];
    __shared__ int    s_act[IT];

    const int tid  = threadIdx.x;
    const int lane = tid & 63;
    const int q    = tid >> 6;           // wave 0..7
    const int j    = tid & (HID - 1);    // hidden unit
    const int half = tid >> 8;           // k-split half 0/1

    const double bias = (half == 0) ? ((double)hid_b[j] + (double)in_b[j]) : 0.0;
    double* const red = &s_scr[0][0][0]; // [IT*HID] view for A-reduce

    // wave-local slot state (waves q < IT own slot q; uniform across the wave)
    int   myitem = -1;
    float mylast = (float)INIT;
    int   sc = 0;

    // ---- initial static claim: slot q <- item blockIdx*IT + q ----
    if (q < IT) {
        const int item = blockIdx.x * IT + q;
        if (item < B) {
            myitem = item;
            float* orow = out + (size_t)item * OUTROW;
            for (int idx = lane; idx < OUTROW; idx += 64) orow[idx] = 0.0f;
            const float4 xv = *(const float4*)&x[(size_t)item * CTX + lane * 4];
            s_x[q][lane * 4 + 0] = (double)xv.x;
            s_x[q][lane * 4 + 1] = (double)xv.y;
            s_x[q][lane * 4 + 2] = (double)xv.z;
            s_x[q][lane * 4 + 3] = (double)xv.w;
            #pragma unroll
            for (int u = 0; u < 4; ++u) s_hid[q][lane + 64 * u] = 1.0;
            if (lane == 0) { s_lastl[q] = INIT; s_act[q] = 1; }
        } else if (lane == 0) { s_lastl[q] = INIT; s_act[q] = 0; }
    }
    __syncthreads();

    for (int iter = 0; iter < (1 << 18); ++iter) {   // cap = hang-protect only
        int lastl[IT], act[IT];
        #pragma unroll
        for (int it = 0; it < IT; ++it) { lastl[it] = s_lastl[it]; act[it] = s_act[it]; }
        if (!(act[0] | act[1] | act[2] | act[3])) break;

        // ---- Phase A: partial pre-activation for unit j, k-half `half`, IT items ----
        double acc[IT];
        #pragma unroll
        for (int it = 0; it < IT; ++it) acc[it] = bias;

        if (half == 0) {
            int sb[IT];
            #pragma unroll
            for (int it = 0; it < IT; ++it) {
                int l = lastl[it]; if (l > CTX) l = CTX;
                sb[it] = l - INIT;                      // in [0, 224]
            }
            #pragma unroll 4
            for (int m = 0; m < INIT; ++m) {
                const double wv = (double)in_W[m * HID + j];
                #pragma unroll
                for (int it = 0; it < IT; ++it)
                    acc[it] = fma(s_x[it][sb[it] + m], wv, acc[it]);
            }
        }
        {
            const int kbeg = (half == 0) ? 0 : KSPLIT;
            const int kend = (half == 0) ? KSPLIT : HID;
            for (int k = kbeg; k < kend; k += 4) {
                double2 hA[IT], hB[IT];
                #pragma unroll
                for (int it = 0; it < IT; ++it) {
                    hA[it] = *(const double2*)&s_hid[it][k];
                    hB[it] = *(const double2*)&s_hid[it][k + 2];
                }
                const double w0 = (double)hid_W[(size_t)(k + 0) * HID + j];
                const double w1 = (double)hid_W[(size_t)(k + 1) * HID + j];
                const double w2 = (double)hid_W[(size_t)(k + 2) * HID + j];
                const double w3 = (double)hid_W[(size_t)(k + 3) * HID + j];
                #pragma unroll
                for (int it = 0; it < IT; ++it) {
                    acc[it] = fma(hA[it].x, w0, acc[it]);
                    acc[it] = fma(hA[it].y, w1, acc[it]);
                    acc[it] = fma(hB[it].x, w2, acc[it]);
                    acc[it] = fma(hB[it].y, w3, acc[it]);
                }
            }
        }

        if (half == 1) {
            #pragma unroll
            for (int it = 0; it < IT; ++it) red[it * HID + j] = acc[it];
        }
        __syncthreads();   // (1) old-s_hid reads done; half1 partials visible

        if (half == 0) {
            #pragma unroll
            for (int it = 0; it < IT; ++it) {
                acc[it] += red[it * HID + j];
                if (act[it]) s_hid[it][j] = (double)tanhf((float)acc[it]);
            }
        }
        __syncthreads();   // (2) new hidden visible; scratch free

        // ---- Phase B: w = hid @ pred_W, split-k over 8 waves ----
        double pacc[IT] = {0.0, 0.0, 0.0, 0.0};
        if (lane < WIN) {
            const int kb = q * 32;
            #pragma unroll 4
            for (int kk = 0; kk < 32; ++kk) {
                const int k = kb + kk;
                const double wv = (double)pred_W[k * WIN + lane];
                #pragma unroll
                for (int it = 0; it < IT; ++it)
                    pacc[it] = fma(s_hid[it][k], wv, pacc[it]);
            }
        }
        #pragma unroll
        for (int it = 0; it < IT; ++it) s_scr[it][q][lane] = pacc[it];
        __syncthreads();   // (3) B partials visible

        // ---- Phase C: wave q owns slot q: fp32 softmax chain + refill ----
        if (q < IT && act[q]) {
            const int it = q;
            float t = -INFINITY;
            if (lane < WIN) {
                const double wv = s_scr[it][0][lane] + s_scr[it][1][lane]
                                + s_scr[it][2][lane] + s_scr[it][3][lane]
                                + s_scr[it][4][lane] + s_scr[it][5][lane]
                                + s_scr[it][6][lane] + s_scr[it][7][lane]
                                + (double)pred_b[lane];
                t = (float)wv * 50000.0f;            // fp32 temp scale like ref
            }
            float mx = t;
            #pragma unroll
            for (int off = 32; off > 0; off >>= 1)
                mx = fmaxf(mx, __shfl_xor(mx, off));
            const float e = (lane < WIN) ? expf(t - mx) : 0.0f;
            float S = e;
            #pragma unroll
            for (int off = 32; off > 0; off >>= 1)
                S += __shfl_xor(S, off);
            const float p = e / S;
            float D = p * (float)lane;
            #pragma unroll
            for (int off = 32; off > 0; off >>= 1)
                D += __shfl_xor(D, off);
            float cur = fminf(D + 1.0f, 63.0f);
            float se = fminf(cur + mylast, 256.0f);
            const int sel = (int)se;

            float* orow = out + (size_t)myitem * OUTROW;
            if (lane < WIN) {
                const int pos = lastl[it] + lane;
                if (pos < sel) {
                    const float msk = 1.0f / (1.0f + expf((float)lane - cur));
                    orow[MSTEPS + pos] = msk * (float)s_x[it][pos];
                }
            }
            const bool done = (se >= 256.0f);        // final step's pt is dropped
            if (lane == 0 && !done) { orow[sc] = se; s_lastl[it] = sel; }
            sc++;
            mylast = se;

            if (done) {
                int nid = 0;
                if (lane == 0) nid = atomicAdd(cnt, 1);
                nid = __shfl(nid, 0);
                if (nid < B) {
                    // refill slot with fresh item nid
                    myitem = nid; mylast = (float)INIT; sc = 0;
                    float* nrow = out + (size_t)nid * OUTROW;
                    for (int idx = lane; idx < OUTROW; idx += 64) nrow[idx] = 0.0f;
                    const float4 xv = *(const float4*)&x[(size_t)nid * CTX + lane * 4];
                    s_x[it][lane * 4 + 0] = (double)xv.x;
                    s_x[it][lane * 4 + 1] = (double)xv.y;
                    s_x[it][lane * 4 + 2] = (double)xv.z;
                    s_x[it][lane * 4 + 3] = (double)xv.w;
                    #pragma unroll
                    for (int u = 0; u < 4; ++u) s_hid[it][lane + 64 * u] = 1.0;
                    if (lane == 0) s_lastl[it] = INIT;   // s_act stays 1
                } else {
                    if (lane == 0) s_act[it] = 0;        // queue empty: slot dies
                }
            }
        }
        __syncthreads();   // (4) state/refill visible; global stores drained
    }
}

extern "C" void kernel_launch(void* const* d_in, const int* in_sizes, int n_in,
                              void* d_out, int out_size, void* d_ws, size_t ws_size,
                              hipStream_t stream) {
    const float* x      = (const float*)d_in[0];
    const float* hid_W  = (const float*)d_in[1];
    const float* hid_b  = (const float*)d_in[2];
    const float* in_W   = (const float*)d_in[3];
    const float* in_b   = (const float*)d_in[4];
    const float* pred_W = (const float*)d_in[5];
    const float* pred_b = (const float*)d_in[6];
    float* out = (float*)d_out;
    int*   cnt = (int*)d_ws;

    const int B = in_sizes[0] / CTX;     // 4096
    init_counter_kernel<<<1, 1, 0, stream>>>(cnt, NSLOT);
    cpp_kernel<<<NBLK, NT, 0, stream>>>(x, hid_W, hid_b, in_W, in_b,
                                        pred_W, pred_b, out, cnt, B);
}